// Round 1
// baseline (265.635 us; speedup 1.0000x reference)
//
#include <hip/hip_runtime.h>

// x_{i+1} = M x_i + c_i,  M = I + dt*A (constant 3x3),  c_i = dt * B d_i
// Parallelized as a 3-pass segmented linear scan (constant-matrix prefix scan).

static constexpr int  N_T   = 2097152;          // N
static constexpr long STEPS = N_T - 1;          // 2097151 Euler steps
static constexpr int  SEG   = 16;               // segment length
static constexpr int  NSEG  = 131072;           // ceil(STEPS/SEG); last segment has 15
static constexpr int  T2    = 1024;             // pass-2 block size
static constexpr int  RPT   = NSEG / T2;        // 128 segments per pass-2 thread

struct Coef {
    float m00,m02,m11,m12,m20,m21,m22;          // nonzeros of M
    float b00,b01,b10,b13,b24;                  // nonzeros of dt*B
};

__device__ __forceinline__ Coef derive(const float* __restrict__ p){
    Coef o;
    const float dt = 3600.0f;
    float Cai=p[0],Cwe=p[1],Cwi=p[2],Re=p[3],Ri=p[4],Rw=p[5],Rg=p[6];
    o.m00 = 1.0f + dt * (-1.0f/Cai*(1.0f/Rg + 1.0f/Ri));
    o.m02 = dt * (1.0f/(Cai*Ri));
    o.m11 = 1.0f + dt * (-1.0f/Cwe*(1.0f/Re + 1.0f/Rw));
    o.m12 = dt * (1.0f/(Cwe*Rw));
    o.m20 = dt * (1.0f/(Cwi*Ri));
    o.m21 = dt * (1.0f/(Cwi*Rw));
    o.m22 = 1.0f + dt * (-1.0f/Cwi*(1.0f/Rw + 1.0f/Ri));
    o.b00 = dt * (1.0f/(Cai*Rg));
    o.b01 = dt * (1.0f/Cai);
    o.b10 = dt * (1.0f/(Cwe*Re));
    o.b13 = dt * (1.0f/Cwe);
    o.b24 = dt * (1.0f/Cwi);
    return o;
}

__device__ __forceinline__ void step(const Coef& C, float& s0, float& s1, float& s2,
                                     float d0, float d1, float d2, float d3, float d4){
    float c0 = fmaf(C.b00, d0, C.b01*(d1+d2));
    float c1 = fmaf(C.b10, d0, C.b13*d3);
    float c2 = C.b24*d4;
    float n0 = fmaf(C.m00, s0, fmaf(C.m02, s2, c0));
    float n1 = fmaf(C.m11, s1, fmaf(C.m12, s2, c1));
    float n2 = fmaf(C.m20, s0, fmaf(C.m21, s1, fmaf(C.m22, s2, c2)));
    s0=n0; s1=n1; s2=n2;
}

// 3x3 double matmul Z = X*Y
__device__ __forceinline__ void mm3(const double* X, const double* Y, double* Z){
    #pragma unroll
    for (int r=0;r<3;++r){
        #pragma unroll
        for (int c=0;c<3;++c){
            Z[r*3+c] = X[r*3+0]*Y[0*3+c] + X[r*3+1]*Y[1*3+c] + X[r*3+2]*Y[2*3+c];
        }
    }
}

// ---------------- pass 1: per-segment partial sums s_k = sum_j M^{L-1-j} c_j --------
__global__ __launch_bounds__(256) void k_pass1(const float* __restrict__ d,
                                               const float* __restrict__ p,
                                               float* __restrict__ sArr){
    int k = blockIdx.x*256 + threadIdx.x;
    if (k >= NSEG) return;
    Coef C = derive(p);
    float s0=0.f, s1=0.f, s2=0.f;
    long i0 = (long)k*SEG;
    if (k != NSEG-1){
        const float4* dp = (const float4*)(d + i0*5);   // 16B-aligned: i0*20 bytes, i0%4==0
        #pragma unroll
        for (int g=0; g<SEG/4; ++g){
            float4 q0=dp[g*5+0], q1=dp[g*5+1], q2=dp[g*5+2], q3=dp[g*5+3], q4=dp[g*5+4];
            step(C,s0,s1,s2, q0.x,q0.y,q0.z,q0.w,q1.x);
            step(C,s0,s1,s2, q1.y,q1.z,q1.w,q2.x,q2.y);
            step(C,s0,s1,s2, q2.z,q2.w,q3.x,q3.y,q3.z);
            step(C,s0,s1,s2, q3.w,q4.x,q4.y,q4.z,q4.w);
        }
    } else {
        for (long i=i0; i<STEPS; ++i){
            const float* r = d + i*5;
            step(C,s0,s1,s2, r[0],r[1],r[2],r[3],r[4]);
        }
    }
    sArr[k*3+0]=s0; sArr[k*3+1]=s1; sArr[k*3+2]=s2;
}

// ---------------- pass 2: scan over segments (single block) -------------------------
__global__ __launch_bounds__(1024) void k_pass2(const float* __restrict__ p,
                                                const float* __restrict__ x0,
                                                const float* __restrict__ sArr,
                                                float* __restrict__ uArr){
    __shared__ float Ish[T2*3];
    int t = threadIdx.x;

    // M in double
    double Cai=p[0],Cwe=p[1],Cwi=p[2],Re=p[3],Ri=p[4],Rw=p[5],Rg=p[6];
    const double dt = 3600.0;
    double Md[9] = {
        1.0 - dt*((1.0/Rg + 1.0/Ri)/Cai), 0.0,                              dt/(Cai*Ri),
        0.0,                              1.0 - dt*((1.0/Re + 1.0/Rw)/Cwe), dt/(Cwe*Rw),
        dt/(Cwi*Ri),                      dt/(Cwi*Rw),                      1.0 - dt*((1.0/Rw + 1.0/Ri)/Cwi)
    };
    double Pd[9], Tm[9];
    #pragma unroll
    for (int i=0;i<9;++i) Pd[i]=Md[i];
    for (int sq=0; sq<4; ++sq){ mm3(Pd,Pd,Tm); for(int i=0;i<9;++i) Pd[i]=Tm[i]; }  // P = M^16
    float Pf[9];
    #pragma unroll
    for (int i=0;i<9;++i) Pf[i]=(float)Pd[i];

    // augmentation of s_0: + P*x0 (folds initial state into the zero-init scan)
    float x00=x0[0], x01=x0[1], x02=x0[2];
    float ax0 = Pf[0]*x00+Pf[1]*x01+Pf[2]*x02;
    float ax1 = Pf[3]*x00+Pf[4]*x01+Pf[5]*x02;
    float ax2 = Pf[6]*x00+Pf[7]*x01+Pf[8]*x02;

    // per-thread serial aggregation of RPT segment sums
    int base = t*RPT;
    float S0=0.f,S1=0.f,S2=0.f;
    for (int j=0;j<RPT;++j){
        int k = base+j;
        float a0=sArr[k*3+0], a1=sArr[k*3+1], a2=sArr[k*3+2];
        if (k==0){ a0+=ax0; a1+=ax1; a2+=ax2; }
        float n0 = Pf[0]*S0+Pf[1]*S1+Pf[2]*S2 + a0;
        float n1 = Pf[3]*S0+Pf[4]*S1+Pf[5]*S2 + a1;
        float n2 = Pf[6]*S0+Pf[7]*S1+Pf[8]*S2 + a2;
        S0=n0;S1=n1;S2=n2;
    }
    Ish[t*3+0]=S0; Ish[t*3+1]=S1; Ish[t*3+2]=S2;

    // Kogge-Stone across threads with Q = P^RPT (doubling each step), f64 powers
    double Qd[9];
    #pragma unroll
    for (int i=0;i<9;++i) Qd[i]=Pd[i];
    for (int sq=0; sq<7; ++sq){ mm3(Qd,Qd,Tm); for(int i=0;i<9;++i) Qd[i]=Tm[i]; }  // P^128

    for (int o=1;o<T2;o<<=1){
        float Qf[9];
        #pragma unroll
        for (int i=0;i<9;++i) Qf[i]=(float)Qd[i];
        __syncthreads();
        float a0=0.f,a1=0.f,a2=0.f;
        if (t>=o){
            float y0=Ish[(t-o)*3+0], y1=Ish[(t-o)*3+1], y2=Ish[(t-o)*3+2];
            a0 = Qf[0]*y0+Qf[1]*y1+Qf[2]*y2;
            a1 = Qf[3]*y0+Qf[4]*y1+Qf[5]*y2;
            a2 = Qf[6]*y0+Qf[7]*y1+Qf[8]*y2;
        }
        __syncthreads();
        if (t>=o){ Ish[t*3+0]+=a0; Ish[t*3+1]+=a1; Ish[t*3+2]+=a2; }
        mm3(Qd,Qd,Tm);
        #pragma unroll
        for(int i=0;i<9;++i) Qd[i]=Tm[i];
    }
    __syncthreads();

    // exclusive prefix = state at this thread's first segment start
    float u0=0.f,u1=0.f,u2=0.f;
    if (t>0){ u0=Ish[(t-1)*3+0]; u1=Ish[(t-1)*3+1]; u2=Ish[(t-1)*3+2]; }

    for (int j=0;j<RPT;++j){
        int k = base+j;
        if (k==0){ uArr[0]=x00; uArr[1]=x01; uArr[2]=x02; }
        else     { uArr[k*3+0]=u0; uArr[k*3+1]=u1; uArr[k*3+2]=u2; }
        float a0=sArr[k*3+0], a1=sArr[k*3+1], a2=sArr[k*3+2];
        if (k==0){ a0+=ax0; a1+=ax1; a2+=ax2; }
        float n0 = Pf[0]*u0+Pf[1]*u1+Pf[2]*u2 + a0;
        float n1 = Pf[3]*u0+Pf[4]*u1+Pf[5]*u2 + a1;
        float n2 = Pf[6]*u0+Pf[7]*u1+Pf[8]*u2 + a2;
        u0=n0;u1=n1;u2=n2;
    }
}

// ---------------- pass 3: replay segments from u_k and write outputs ----------------
__global__ __launch_bounds__(256) void k_pass3(const float* __restrict__ d,
                                               const float* __restrict__ p,
                                               const float* __restrict__ uArr,
                                               const float* __restrict__ x0,
                                               float* __restrict__ out){
    int k = blockIdx.x*256 + threadIdx.x;
    if (k >= NSEG) return;
    Coef C = derive(p);
    float s0=uArr[k*3+0], s1=uArr[k*3+1], s2=uArr[k*3+2];
    long i0 = (long)k*SEG;
    if (k==0){ out[0]=x0[0]; out[1]=x0[1]; out[2]=x0[2]; }
    if (k != NSEG-1){
        const float4* dp = (const float4*)(d + i0*5);
        float* op = out + (i0+1)*3;
        #pragma unroll
        for (int g=0; g<SEG/4; ++g){
            float4 q0=dp[g*5+0], q1=dp[g*5+1], q2=dp[g*5+2], q3=dp[g*5+3], q4=dp[g*5+4];
            step(C,s0,s1,s2, q0.x,q0.y,q0.z,q0.w,q1.x);
            op[(g*4+0)*3+0]=s0; op[(g*4+0)*3+1]=s1; op[(g*4+0)*3+2]=s2;
            step(C,s0,s1,s2, q1.y,q1.z,q1.w,q2.x,q2.y);
            op[(g*4+1)*3+0]=s0; op[(g*4+1)*3+1]=s1; op[(g*4+1)*3+2]=s2;
            step(C,s0,s1,s2, q2.z,q2.w,q3.x,q3.y,q3.z);
            op[(g*4+2)*3+0]=s0; op[(g*4+2)*3+1]=s1; op[(g*4+2)*3+2]=s2;
            step(C,s0,s1,s2, q3.w,q4.x,q4.y,q4.z,q4.w);
            op[(g*4+3)*3+0]=s0; op[(g*4+3)*3+1]=s1; op[(g*4+3)*3+2]=s2;
        }
    } else {
        for (long i=i0; i<STEPS; ++i){
            const float* r = d + i*5;
            step(C,s0,s1,s2, r[0],r[1],r[2],r[3],r[4]);
            out[(i+1)*3+0]=s0; out[(i+1)*3+1]=s1; out[(i+1)*3+2]=s2;
        }
    }
}

extern "C" void kernel_launch(void* const* d_in, const int* in_sizes, int n_in,
                              void* d_out, int out_size, void* d_ws, size_t ws_size,
                              hipStream_t stream) {
    const float* params = (const float*)d_in[0];
    const float* x0     = (const float*)d_in[1];
    const float* d      = (const float*)d_in[2];
    float* out  = (float*)d_out;
    float* sArr = (float*)d_ws;              // NSEG*3 floats
    float* uArr = sArr + (size_t)NSEG*3;     // NSEG*3 floats  (total ~3 MB of ws)

    k_pass1<<<NSEG/256, 256, 0, stream>>>(d, params, sArr);
    k_pass2<<<1, T2, 0, stream>>>(params, x0, sArr, uArr);
    k_pass3<<<NSEG/256, 256, 0, stream>>>(d, params, uArr, x0, out);
}

// Round 2
// 49.719 us; speedup vs baseline: 5.3427x; 5.3427x over previous
//
#include <hip/hip_runtime.h>

// x_{i+1} = M x_i + c_i,  M = I + dt*A (constant 3x3),  c_i = dt * B d_i
// 3-level segmented linear scan:
//   pass1: per-segment sums (SEG=16) + per-block (256-seg) totals via LDS Kogge-Stone
//   pass2: scan 512 block totals (single tiny block)
//   pass3: block-level scan seeded by carry, replay 16 steps, write outputs

static constexpr int  N_T   = 2097152;          // N
static constexpr long STEPS = N_T - 1;          // 2097151 Euler steps
static constexpr int  SEG   = 16;               // segment length
static constexpr int  NSEG  = 131072;           // segments (last has 15 steps)
static constexpr int  BLK   = 256;              // threads per block = segments per block
static constexpr int  NBLK  = NSEG / BLK;       // 512 blocks

struct Coef {
    float m00,m02,m11,m12,m20,m21,m22;          // nonzeros of M
    float b00,b01,b10,b13,b24;                  // nonzeros of dt*B
};

__device__ __forceinline__ Coef derive(const float* __restrict__ p){
    Coef o;
    const float dt = 3600.0f;
    float Cai=p[0],Cwe=p[1],Cwi=p[2],Re=p[3],Ri=p[4],Rw=p[5],Rg=p[6];
    o.m00 = 1.0f + dt * (-1.0f/Cai*(1.0f/Rg + 1.0f/Ri));
    o.m02 = dt * (1.0f/(Cai*Ri));
    o.m11 = 1.0f + dt * (-1.0f/Cwe*(1.0f/Re + 1.0f/Rw));
    o.m12 = dt * (1.0f/(Cwe*Rw));
    o.m20 = dt * (1.0f/(Cwi*Ri));
    o.m21 = dt * (1.0f/(Cwi*Rw));
    o.m22 = 1.0f + dt * (-1.0f/Cwi*(1.0f/Rw + 1.0f/Ri));
    o.b00 = dt * (1.0f/(Cai*Rg));
    o.b01 = dt * (1.0f/Cai);
    o.b10 = dt * (1.0f/(Cwe*Re));
    o.b13 = dt * (1.0f/Cwe);
    o.b24 = dt * (1.0f/Cwi);
    return o;
}

__device__ __forceinline__ void step(const Coef& C, float& s0, float& s1, float& s2,
                                     float d0, float d1, float d2, float d3, float d4){
    float c0 = fmaf(C.b00, d0, C.b01*(d1+d2));
    float c1 = fmaf(C.b10, d0, C.b13*d3);
    float c2 = C.b24*d4;
    float n0 = fmaf(C.m00, s0, fmaf(C.m02, s2, c0));
    float n1 = fmaf(C.m11, s1, fmaf(C.m12, s2, c1));
    float n2 = fmaf(C.m20, s0, fmaf(C.m21, s1, fmaf(C.m22, s2, c2)));
    s0=n0; s1=n1; s2=n2;
}

__device__ __forceinline__ void mm3(const double* X, const double* Y, double* Z){
    #pragma unroll
    for (int r=0;r<3;++r){
        #pragma unroll
        for (int c=0;c<3;++c){
            Z[r*3+c] = X[r*3+0]*Y[0*3+c] + X[r*3+1]*Y[1*3+c] + X[r*3+2]*Y[2*3+c];
        }
    }
}

__device__ __forceinline__ void msq(double* X){          // X = X*X
    double T[9]; mm3(X,X,T);
    #pragma unroll
    for (int i=0;i<9;++i) X[i]=T[i];
}

__device__ __forceinline__ void computeM(const float* __restrict__ p, double* Md){
    double Cai=p[0],Cwe=p[1],Cwi=p[2],Re=p[3],Ri=p[4],Rw=p[5],Rg=p[6];
    const double dt = 3600.0;
    Md[0]=1.0 - dt*((1.0/Rg + 1.0/Ri)/Cai); Md[1]=0.0;                              Md[2]=dt/(Cai*Ri);
    Md[3]=0.0;                              Md[4]=1.0 - dt*((1.0/Re + 1.0/Rw)/Cwe); Md[5]=dt/(Cwe*Rw);
    Md[6]=dt/(Cwi*Ri);                      Md[7]=dt/(Cwi*Rw);                      Md[8]=1.0 - dt*((1.0/Rw + 1.0/Ri)/Cwi);
}

// Kogge-Stone inclusive scan over nthr threads in LDS; combine: v_t = Q * v_{t-o} + v_t,
// Q doubling from Qd (f64, squared between levels). v kept in registers; Ish mirrors it.
__device__ __forceinline__ void lds_scan(float* Ish, int t, int nthr,
                                         double* Qd, float& v0, float& v1, float& v2){
    Ish[t*3+0]=v0; Ish[t*3+1]=v1; Ish[t*3+2]=v2;
    for (int o=1;o<nthr;o<<=1){
        float Qf[9];
        #pragma unroll
        for (int i=0;i<9;++i) Qf[i]=(float)Qd[i];
        __syncthreads();
        float y0=0.f,y1=0.f,y2=0.f;
        if (t>=o){ y0=Ish[(t-o)*3+0]; y1=Ish[(t-o)*3+1]; y2=Ish[(t-o)*3+2]; }
        __syncthreads();
        if (t>=o){
            v0 = Qf[0]*y0+Qf[1]*y1+Qf[2]*y2 + v0;
            v1 = Qf[3]*y0+Qf[4]*y1+Qf[5]*y2 + v1;
            v2 = Qf[6]*y0+Qf[7]*y1+Qf[8]*y2 + v2;
            Ish[t*3+0]=v0; Ish[t*3+1]=v1; Ish[t*3+2]=v2;
        }
        msq(Qd);
    }
    __syncthreads();
}

// ---------------- pass 1: segment sums + block totals -------------------------------
__global__ __launch_bounds__(256) void k_pass1(const float* __restrict__ d,
                                               const float* __restrict__ p,
                                               float* __restrict__ sArr,
                                               float* __restrict__ blkSum){
    int t = threadIdx.x, b = blockIdx.x;
    int k = b*BLK + t;
    Coef C = derive(p);
    float s0=0.f, s1=0.f, s2=0.f;
    long i0 = (long)k*SEG;
    if (k != NSEG-1){
        const float4* dp = (const float4*)(d + i0*5);   // k*80 floats -> 16B aligned
        #pragma unroll
        for (int g=0; g<SEG/4; ++g){
            float4 q0=dp[g*5+0], q1=dp[g*5+1], q2=dp[g*5+2], q3=dp[g*5+3], q4=dp[g*5+4];
            step(C,s0,s1,s2, q0.x,q0.y,q0.z,q0.w,q1.x);
            step(C,s0,s1,s2, q1.y,q1.z,q1.w,q2.x,q2.y);
            step(C,s0,s1,s2, q2.z,q2.w,q3.x,q3.y,q3.z);
            step(C,s0,s1,s2, q3.w,q4.x,q4.y,q4.z,q4.w);
        }
    } else {
        for (long i=i0; i<STEPS; ++i){
            const float* r = d + i*5;
            step(C,s0,s1,s2, r[0],r[1],r[2],r[3],r[4]);
        }
    }
    sArr[k*3+0]=s0; sArr[k*3+1]=s1; sArr[k*3+2]=s2;

    // block scan -> block total (thread BLK-1's inclusive value)
    __shared__ float Ish[BLK*3];
    double Pd[9]; computeM(p, Pd);
    msq(Pd); msq(Pd); msq(Pd); msq(Pd);                 // P = M^16
    double Qd[9];
    #pragma unroll
    for (int i=0;i<9;++i) Qd[i]=Pd[i];
    float v0=s0, v1=s1, v2=s2;
    lds_scan(Ish, t, BLK, Qd, v0, v1, v2);
    if (t==BLK-1){ blkSum[b*3+0]=v0; blkSum[b*3+1]=v1; blkSum[b*3+2]=v2; }
}

// ---------------- pass 2: scan 512 block totals -> block carries --------------------
__global__ __launch_bounds__(512) void k_pass2(const float* __restrict__ p,
                                               const float* __restrict__ x0,
                                               const float* __restrict__ blkSum,
                                               float* __restrict__ carry){
    __shared__ float Ish[NBLK*3];
    int t = threadIdx.x;
    double Rd[9]; computeM(p, Rd);
    #pragma unroll
    for (int i=0;i<12;++i) msq(Rd);                     // R = M^4096 (one block = 256*16 steps)
    float x00=x0[0], x01=x0[1], x02=x0[2];
    float v0=blkSum[t*3+0], v1=blkSum[t*3+1], v2=blkSum[t*3+2];
    if (t==0){
        float Rf[9];
        #pragma unroll
        for (int i=0;i<9;++i) Rf[i]=(float)Rd[i];
        v0 += Rf[0]*x00+Rf[1]*x01+Rf[2]*x02;            // fold initial state into elem 0
        v1 += Rf[3]*x00+Rf[4]*x01+Rf[5]*x02;
        v2 += Rf[6]*x00+Rf[7]*x01+Rf[8]*x02;
    }
    double Qd[9];
    #pragma unroll
    for (int i=0;i<9;++i) Qd[i]=Rd[i];
    lds_scan(Ish, t, NBLK, Qd, v0, v1, v2);
    // carry[b] = state at start of block b
    if (t==0){ carry[0]=x00; carry[1]=x01; carry[2]=x02; }
    else     { carry[t*3+0]=Ish[(t-1)*3+0]; carry[t*3+1]=Ish[(t-1)*3+1]; carry[t*3+2]=Ish[(t-1)*3+2]; }
}

// ---------------- pass 3: block scan seeded by carry, replay, write out -------------
__global__ __launch_bounds__(256) void k_pass3(const float* __restrict__ d,
                                               const float* __restrict__ p,
                                               const float* __restrict__ sArr,
                                               const float* __restrict__ carry,
                                               const float* __restrict__ x0,
                                               float* __restrict__ out){
    int t = threadIdx.x, b = blockIdx.x;
    int k = b*BLK + t;
    Coef C = derive(p);

    __shared__ float Ish[BLK*3];
    double Pd[9]; computeM(p, Pd);
    msq(Pd); msq(Pd); msq(Pd); msq(Pd);                 // P = M^16
    float U0=carry[b*3+0], U1=carry[b*3+1], U2=carry[b*3+2];
    float v0=sArr[k*3+0], v1=sArr[k*3+1], v2=sArr[k*3+2];
    if (t==0){
        float Pf[9];
        #pragma unroll
        for (int i=0;i<9;++i) Pf[i]=(float)Pd[i];
        v0 += Pf[0]*U0+Pf[1]*U1+Pf[2]*U2;
        v1 += Pf[3]*U0+Pf[4]*U1+Pf[5]*U2;
        v2 += Pf[6]*U0+Pf[7]*U1+Pf[8]*U2;
    }
    double Qd[9];
    #pragma unroll
    for (int i=0;i<9;++i) Qd[i]=Pd[i];
    lds_scan(Ish, t, BLK, Qd, v0, v1, v2);

    // state at this segment's start
    float s0,s1,s2;
    if (t==0){ s0=U0; s1=U1; s2=U2; }
    else     { s0=Ish[(t-1)*3+0]; s1=Ish[(t-1)*3+1]; s2=Ish[(t-1)*3+2]; }

    long i0 = (long)k*SEG;
    if (k==0){ out[0]=x0[0]; out[1]=x0[1]; out[2]=x0[2]; }
    if (k != NSEG-1){
        const float4* dp = (const float4*)(d + i0*5);
        float* op = out + (i0+1)*3;
        #pragma unroll
        for (int g=0; g<SEG/4; ++g){
            float4 q0=dp[g*5+0], q1=dp[g*5+1], q2=dp[g*5+2], q3=dp[g*5+3], q4=dp[g*5+4];
            step(C,s0,s1,s2, q0.x,q0.y,q0.z,q0.w,q1.x);
            op[(g*4+0)*3+0]=s0; op[(g*4+0)*3+1]=s1; op[(g*4+0)*3+2]=s2;
            step(C,s0,s1,s2, q1.y,q1.z,q1.w,q2.x,q2.y);
            op[(g*4+1)*3+0]=s0; op[(g*4+1)*3+1]=s1; op[(g*4+1)*3+2]=s2;
            step(C,s0,s1,s2, q2.z,q2.w,q3.x,q3.y,q3.z);
            op[(g*4+2)*3+0]=s0; op[(g*4+2)*3+1]=s1; op[(g*4+2)*3+2]=s2;
            step(C,s0,s1,s2, q3.w,q4.x,q4.y,q4.z,q4.w);
            op[(g*4+3)*3+0]=s0; op[(g*4+3)*3+1]=s1; op[(g*4+3)*3+2]=s2;
        }
    } else {
        for (long i=i0; i<STEPS; ++i){
            const float* r = d + i*5;
            step(C,s0,s1,s2, r[0],r[1],r[2],r[3],r[4]);
            out[(i+1)*3+0]=s0; out[(i+1)*3+1]=s1; out[(i+1)*3+2]=s2;
        }
    }
}

extern "C" void kernel_launch(void* const* d_in, const int* in_sizes, int n_in,
                              void* d_out, int out_size, void* d_ws, size_t ws_size,
                              hipStream_t stream) {
    const float* params = (const float*)d_in[0];
    const float* x0     = (const float*)d_in[1];
    const float* d      = (const float*)d_in[2];
    float* out    = (float*)d_out;
    float* sArr   = (float*)d_ws;                       // NSEG*3 floats (~1.5 MB)
    float* blkSum = sArr + (size_t)NSEG*3;              // NBLK*3 floats
    float* carry  = blkSum + (size_t)NBLK*3;            // NBLK*3 floats

    k_pass1<<<NBLK, BLK, 0, stream>>>(d, params, sArr, blkSum);
    k_pass2<<<1, NBLK, 0, stream>>>(params, x0, blkSum, carry);
    k_pass3<<<NBLK, BLK, 0, stream>>>(d, params, sArr, carry, x0, out);
}

// Round 3
// 45.844 us; speedup vs baseline: 5.7943x; 1.0845x over previous
//
#include <hip/hip_runtime.h>

// x_{i+1} = M x_i + c_i,  M = I + dt*A (constant 3x3),  c_i = dt * B d_i
// 2-kernel segmented linear scan:
//   K1: per-block (2048-step) totals via LDS tree reduction      (reads d, writes 12 KB)
//   K2: every block scans the 1024 totals itself -> carry, then
//       in-block Kogge-Stone over 8-step segments, replay, write (reads d+totals, writes out)

static constexpr long STEPS = 2097151;        // N-1 Euler steps
static constexpr int  SEG   = 8;              // steps per thread
static constexpr int  TPB   = 256;            // threads per block
static constexpr int  NBLK  = 1024;           // blocks; chunk = 2048 steps
static constexpr long NSEGT = (long)NBLK*TPB; // 262144 segments (last has 7 live steps)

struct Coef {
    float m00,m02,m11,m12,m20,m21,m22;        // nonzeros of M
    float b00,b01,b10,b13,b24;                // nonzeros of dt*B
};

__device__ __forceinline__ Coef derive(const float* __restrict__ p){
    Coef o;
    const float dt = 3600.0f;
    float Cai=p[0],Cwe=p[1],Cwi=p[2],Re=p[3],Ri=p[4],Rw=p[5],Rg=p[6];
    o.m00 = 1.0f + dt * (-1.0f/Cai*(1.0f/Rg + 1.0f/Ri));
    o.m02 = dt * (1.0f/(Cai*Ri));
    o.m11 = 1.0f + dt * (-1.0f/Cwe*(1.0f/Re + 1.0f/Rw));
    o.m12 = dt * (1.0f/(Cwe*Rw));
    o.m20 = dt * (1.0f/(Cwi*Ri));
    o.m21 = dt * (1.0f/(Cwi*Rw));
    o.m22 = 1.0f + dt * (-1.0f/Cwi*(1.0f/Rw + 1.0f/Ri));
    o.b00 = dt * (1.0f/(Cai*Rg));
    o.b01 = dt * (1.0f/Cai);
    o.b10 = dt * (1.0f/(Cwe*Re));
    o.b13 = dt * (1.0f/Cwe);
    o.b24 = dt * (1.0f/Cwi);
    return o;
}

__device__ __forceinline__ void step(const Coef& C, float& s0, float& s1, float& s2,
                                     float d0, float d1, float d2, float d3, float d4){
    float c0 = fmaf(C.b00, d0, C.b01*(d1+d2));
    float c1 = fmaf(C.b10, d0, C.b13*d3);
    float c2 = C.b24*d4;
    float n0 = fmaf(C.m00, s0, fmaf(C.m02, s2, c0));
    float n1 = fmaf(C.m11, s1, fmaf(C.m12, s2, c1));
    float n2 = fmaf(C.m20, s0, fmaf(C.m21, s1, fmaf(C.m22, s2, c2)));
    s0=n0; s1=n1; s2=n2;
}

__device__ __forceinline__ void mm3(const double* X, const double* Y, double* Z){
    #pragma unroll
    for (int r=0;r<3;++r)
        #pragma unroll
        for (int c=0;c<3;++c)
            Z[r*3+c] = X[r*3+0]*Y[0*3+c] + X[r*3+1]*Y[1*3+c] + X[r*3+2]*Y[2*3+c];
}
__device__ __forceinline__ void msq(double* X){ double T[9]; mm3(X,X,T);
    #pragma unroll
    for (int i=0;i<9;++i) X[i]=T[i]; }

__device__ __forceinline__ void computeM(const float* __restrict__ p, double* Md){
    double Cai=p[0],Cwe=p[1],Cwi=p[2],Re=p[3],Ri=p[4],Rw=p[5],Rg=p[6];
    const double dt = 3600.0;
    Md[0]=1.0 - dt*((1.0/Rg + 1.0/Ri)/Cai); Md[1]=0.0;                              Md[2]=dt/(Cai*Ri);
    Md[3]=0.0;                              Md[4]=1.0 - dt*((1.0/Re + 1.0/Rw)/Cwe); Md[5]=dt/(Cwe*Rw);
    Md[6]=dt/(Cwi*Ri);                      Md[7]=dt/(Cwi*Rw);                      Md[8]=1.0 - dt*((1.0/Rw + 1.0/Ri)/Cwi);
}

// thread's 8-step segment sum from global memory (all loads in-bounds: d has N=STEPS+1 rows)
__device__ __forceinline__ void seg_sum(const float* __restrict__ d, long i0, const Coef& C,
                                        float& s0, float& s1, float& s2){
    const float4* dp = (const float4*)(d + i0*5);     // i0 multiple of 8 -> 160B aligned
    s0=0.f; s1=0.f; s2=0.f;
    #pragma unroll
    for (int g=0; g<2; ++g){
        float4 q0=dp[g*5+0], q1=dp[g*5+1], q2=dp[g*5+2], q3=dp[g*5+3], q4=dp[g*5+4];
        step(C,s0,s1,s2, q0.x,q0.y,q0.z,q0.w,q1.x);
        step(C,s0,s1,s2, q1.y,q1.z,q1.w,q2.x,q2.y);
        step(C,s0,s1,s2, q2.z,q2.w,q3.x,q3.y,q3.z);
        step(C,s0,s1,s2, q3.w,q4.x,q4.y,q4.z,q4.w);
    }
}

// ---------------- K1: per-block totals (tree reduction) -----------------------------
__global__ __launch_bounds__(256) void k_tot(const float* __restrict__ d,
                                             const float* __restrict__ p,
                                             float* __restrict__ blkTot){
    int t = threadIdx.x, b = blockIdx.x;
    long k = (long)b*TPB + t;
    Coef C = derive(p);
    float s0,s1,s2;
    seg_sum(d, k*SEG, C, s0,s1,s2);       // last thread's 8th step spills into unused total

    __shared__ float a[TPB*3];
    a[t*3+0]=s0; a[t*3+1]=s1; a[t*3+2]=s2;
    double Qd[9]; computeM(p, Qd);
    msq(Qd); msq(Qd); msq(Qd);            // M^8
    __syncthreads();
    for (int off=1; off<TPB; off<<=1){
        float Qf[9];
        #pragma unroll
        for (int i=0;i<9;++i) Qf[i]=(float)Qd[i];
        if ((t & (2*off-1))==0){
            float l0=a[t*3+0], l1=a[t*3+1], l2=a[t*3+2];
            float r0=a[(t+off)*3+0], r1=a[(t+off)*3+1], r2=a[(t+off)*3+2];
            a[t*3+0] = r0 + Qf[0]*l0+Qf[1]*l1+Qf[2]*l2;
            a[t*3+1] = r1 + Qf[3]*l0+Qf[4]*l1+Qf[5]*l2;
            a[t*3+2] = r2 + Qf[6]*l0+Qf[7]*l1+Qf[8]*l2;
        }
        msq(Qd);
        __syncthreads();
    }
    if (t==0){ blkTot[b*3+0]=a[0]; blkTot[b*3+1]=a[1]; blkTot[b*3+2]=a[2]; }
}

// ---------------- K2: per-block carry from totals + scan + replay + write -----------
__global__ __launch_bounds__(256) void k_scan(const float* __restrict__ d,
                                              const float* __restrict__ p,
                                              const float* __restrict__ blkTot,
                                              const float* __restrict__ x0,
                                              float* __restrict__ out){
    __shared__ float Tl[NBLK*3];          // 12 KB: block totals
    __shared__ float Wl[TPB*3];           // 3 KB: 4-block pre-combined, then KS scan
    __shared__ float Sl[TPB*3];           // 3 KB: in-block segment scan
    __shared__ float powA[8][9];          // M^(8*2^l)
    __shared__ float powB[8][9];          // M^(8192*2^l)
    __shared__ float Rm[9];               // M^2048

    int t = threadIdx.x, b = blockIdx.x;
    long k = (long)b*TPB + t;
    long i0 = k*SEG;
    Coef C = derive(p);

    // cooperative load of totals
    for (int i=t; i<NBLK*3; i+=TPB) Tl[i] = blkTot[i];

    // lane 0 builds all power tables in f64
    if (t==0){
        double Qd[9]; computeM(p, Qd);
        msq(Qd); msq(Qd); msq(Qd);                        // M^8
        for (int l=0;l<8;++l){
            #pragma unroll
            for (int i=0;i<9;++i) powA[l][i]=(float)Qd[i];
            msq(Qd);                                      // after loop: M^2048
        }
        #pragma unroll
        for (int i=0;i<9;++i) Rm[i]=(float)Qd[i];
        msq(Qd); msq(Qd);                                 // M^8192
        for (int l=0;l<8;++l){
            #pragma unroll
            for (int i=0;i<9;++i) powB[l][i]=(float)Qd[i];
            msq(Qd);
        }
    }
    __syncthreads();

    float x00=x0[0], x01=x0[1], x02=x0[2];
    if (t==0){                                            // fold x0 into block 0's total
        Tl[0] += Rm[0]*x00+Rm[1]*x01+Rm[2]*x02;
        Tl[1] += Rm[3]*x00+Rm[4]*x01+Rm[5]*x02;
        Tl[2] += Rm[6]*x00+Rm[7]*x01+Rm[8]*x02;
    }
    __syncthreads();

    // pre-combine 4 totals per thread: W_t covers blocks [4t..4t+3]
    float w0=Tl[(4*t)*3+0], w1=Tl[(4*t)*3+1], w2=Tl[(4*t)*3+2];
    #pragma unroll
    for (int j=1;j<4;++j){
        float n0 = Tl[(4*t+j)*3+0] + Rm[0]*w0+Rm[1]*w1+Rm[2]*w2;
        float n1 = Tl[(4*t+j)*3+1] + Rm[3]*w0+Rm[4]*w1+Rm[5]*w2;
        float n2 = Tl[(4*t+j)*3+2] + Rm[6]*w0+Rm[7]*w1+Rm[8]*w2;
        w0=n0; w1=n1; w2=n2;
    }
    Wl[t*3+0]=w0; Wl[t*3+1]=w1; Wl[t*3+2]=w2;
    __syncthreads();
    // Kogge-Stone inclusive scan over 256 entries (element = 8192 steps)
    for (int l=0;l<8;++l){
        int off = 1<<l;
        float y0=0.f,y1=0.f,y2=0.f;
        if (t>=off){ y0=Wl[(t-off)*3+0]; y1=Wl[(t-off)*3+1]; y2=Wl[(t-off)*3+2]; }
        __syncthreads();
        if (t>=off){
            w0 += powB[l][0]*y0+powB[l][1]*y1+powB[l][2]*y2;
            w1 += powB[l][3]*y0+powB[l][4]*y1+powB[l][5]*y2;
            w2 += powB[l][6]*y0+powB[l][7]*y1+powB[l][8]*y2;
            Wl[t*3+0]=w0; Wl[t*3+1]=w1; Wl[t*3+2]=w2;
        }
        __syncthreads();
    }

    // carry for this block = state at step b*2048 (uniform across block)
    float c0,c1,c2;
    if (b==0){ c0=x00; c1=x01; c2=x02; }
    else {
        int e = b-1, q = e>>2;
        float P0=0.f,P1=0.f,P2=0.f;
        if (q>0){ P0=Wl[(q-1)*3+0]; P1=Wl[(q-1)*3+1]; P2=Wl[(q-1)*3+2]; }
        for (int j=4*q; j<=e; ++j){
            float n0 = Tl[j*3+0] + Rm[0]*P0+Rm[1]*P1+Rm[2]*P2;
            float n1 = Tl[j*3+1] + Rm[3]*P0+Rm[4]*P1+Rm[5]*P2;
            float n2 = Tl[j*3+2] + Rm[6]*P0+Rm[7]*P1+Rm[8]*P2;
            P0=n0; P1=n1; P2=n2;
        }
        c0=P0; c1=P1; c2=P2;
    }

    // in-block scan over 8-step segments
    float s0,s1,s2;
    seg_sum(d, i0, C, s0,s1,s2);
    float v0=s0, v1=s1, v2=s2;
    if (t==0){                                            // fold carry: + M^8 * carry
        v0 += powA[0][0]*c0+powA[0][1]*c1+powA[0][2]*c2;
        v1 += powA[0][3]*c0+powA[0][4]*c1+powA[0][5]*c2;
        v2 += powA[0][6]*c0+powA[0][7]*c1+powA[0][8]*c2;
    }
    Sl[t*3+0]=v0; Sl[t*3+1]=v1; Sl[t*3+2]=v2;
    __syncthreads();
    for (int l=0;l<8;++l){
        int off = 1<<l;
        float y0=0.f,y1=0.f,y2=0.f;
        if (t>=off){ y0=Sl[(t-off)*3+0]; y1=Sl[(t-off)*3+1]; y2=Sl[(t-off)*3+2]; }
        __syncthreads();
        if (t>=off){
            v0 += powA[l][0]*y0+powA[l][1]*y1+powA[l][2]*y2;
            v1 += powA[l][3]*y0+powA[l][4]*y1+powA[l][5]*y2;
            v2 += powA[l][6]*y0+powA[l][7]*y1+powA[l][8]*y2;
            Sl[t*3+0]=v0; Sl[t*3+1]=v1; Sl[t*3+2]=v2;
        }
        __syncthreads();
    }

    // segment start state, replay, write
    float g0,g1,g2;
    if (t==0){ g0=c0; g1=c1; g2=c2; }
    else     { g0=Sl[(t-1)*3+0]; g1=Sl[(t-1)*3+1]; g2=Sl[(t-1)*3+2]; }

    if (k==0){ out[0]=x00; out[1]=x01; out[2]=x02; }
    const float4* dp = (const float4*)(d + i0*5);
    float* op = out + (i0+1)*3;
    bool full = (k != NSEGT-1);
    #pragma unroll
    for (int g=0; g<2; ++g){
        float4 q0=dp[g*5+0], q1=dp[g*5+1], q2=dp[g*5+2], q3=dp[g*5+3], q4=dp[g*5+4];
        step(C,g0,g1,g2, q0.x,q0.y,q0.z,q0.w,q1.x);
        op[(g*4+0)*3+0]=g0; op[(g*4+0)*3+1]=g1; op[(g*4+0)*3+2]=g2;
        step(C,g0,g1,g2, q1.y,q1.z,q1.w,q2.x,q2.y);
        op[(g*4+1)*3+0]=g0; op[(g*4+1)*3+1]=g1; op[(g*4+1)*3+2]=g2;
        step(C,g0,g1,g2, q2.z,q2.w,q3.x,q3.y,q3.z);
        op[(g*4+2)*3+0]=g0; op[(g*4+2)*3+1]=g1; op[(g*4+2)*3+2]=g2;
        step(C,g0,g1,g2, q3.w,q4.x,q4.y,q4.z,q4.w);
        if (g==1 && !full) break;                         // last thread: only 7 writes
        op[(g*4+3)*3+0]=g0; op[(g*4+3)*3+1]=g1; op[(g*4+3)*3+2]=g2;
    }
}

extern "C" void kernel_launch(void* const* d_in, const int* in_sizes, int n_in,
                              void* d_out, int out_size, void* d_ws, size_t ws_size,
                              hipStream_t stream) {
    const float* params = (const float*)d_in[0];
    const float* x0     = (const float*)d_in[1];
    const float* d      = (const float*)d_in[2];
    float* out    = (float*)d_out;
    float* blkTot = (float*)d_ws;                         // NBLK*3 floats (12 KB)

    k_tot <<<NBLK, TPB, 0, stream>>>(d, params, blkTot);
    k_scan<<<NBLK, TPB, 0, stream>>>(d, params, blkTot, x0, out);
}